// Round 8
// baseline (1853.862 us; speedup 1.0000x reference)
//
#include <hip/hip_runtime.h>

#define HDIM 256
#define KSTEPS 30
#define RPB 32            // rows per block
#define NTHR 512          // 8 waves

typedef _Float16 f16x8 __attribute__((ext_vector_type(8)));
typedef float f32x4 __attribute__((ext_vector_type(4)));
typedef float f32x16 __attribute__((ext_vector_type(16)));

#define ZV16 (f32x16){0,0,0,0,0,0,0,0,0,0,0,0,0,0,0,0}

__device__ __forceinline__ f32x4 mfma16(f16x8 a, f16x8 b, f32x4 c) {
  return __builtin_amdgcn_mfma_f32_16x16x32_f16(a, b, c, 0, 0, 0);
}
__device__ __forceinline__ f32x16 mfma32(f16x8 a, f16x8 b, f32x16 c) {
  return __builtin_amdgcn_mfma_f32_32x32x16_f16(a, b, c, 0, 0, 0);
}

// fast transcendentals: v_exp_f32 / v_rcp_f32 (~2 ULP; threshold is 0.037)
__device__ __forceinline__ float fsigm(float x) {
  return __builtin_amdgcn_rcpf(1.0f + __expf(-x));
}
__device__ __forceinline__ float ftanh(float x) {
  float t = __expf(2.0f * x);                 // inf for big x -> rcp=0 -> 1
  return 1.0f - 2.0f * __builtin_amdgcn_rcpf(t + 1.0f);
}
__device__ __forceinline__ float softplusf(float x) {
  return fmaxf(x, 0.0f) + log1pf(__expf(-fabsf(x)));
}

// swizzled byte offset for a [32][256] fp16 LDS tile (row stride 512B)
__device__ __forceinline__ int swz(int r, int c) {
  return r * 512 + ((c * 2) ^ ((r & 7) << 4));
}

__device__ __forceinline__ void wrsplit(char* hi, char* lo, int off, float v) {
  _Float16 h = (_Float16)v;
  *(_Float16*)(hi + off) = h;
  *(_Float16*)(lo + off) = (_Float16)(v - (float)h);
}
__device__ __forceinline__ float rdpair(const char* hi, const char* lo, int off) {
  return (float)*(const _Float16*)(hi + off) + (float)*(const _Float16*)(lo + off);
}

// ---------------- prep: conversions + MFMA-order weight packing + teW ----------------
// Packed recurrent-weight layout (fp16):
//   e = (((w*16 + t)*3 + g)*64 + lane)*8 + j
//   src row = w*32 + (lane&31) + g*256 ; src col = t*16 + (lane>>5)*8 + j
// so each (wave w, tile t, gate g) is one contiguous 1KB = one coalesced
// global_load_dwordx4 per wave straight into the mfma32 B-fragment.
__global__ __launch_bounds__(256) void prep_kernel(
    const float* __restrict__ W1, const float* __restrict__ W2,
    const float* __restrict__ Wih0, const float* __restrict__ Whh0,
    const float* __restrict__ Wih1, const float* __restrict__ Whh1,
    const float* __restrict__ hf,
    _Float16* __restrict__ Whh0p, _Float16* __restrict__ Wih1p,
    _Float16* __restrict__ Whh1p,
    _Float16* __restrict__ W1h, _Float16* __restrict__ W1l,
    _Float16* __restrict__ W2h, _Float16* __restrict__ W2l,
    _Float16* __restrict__ Wih0hh, _Float16* __restrict__ Wih0hl,
    _Float16* __restrict__ hfh, _Float16* __restrict__ hfl,
    float* __restrict__ teW, int B)
{
  int e = blockIdx.x * 256 + threadIdx.x;
  if (e < 3*196608) {
    int m = e / 196608, p = e % 196608;
    int j = p & 7, lane = (p >> 3) & 63;
    int q = p >> 9;
    int g = q % 3, tt = q / 3;
    int t = tt & 15, w = tt >> 4;
    int row = w*32 + (lane & 31) + g*256;
    int col = t*16 + (lane >> 5)*8 + j;
    const float* src = (m == 0) ? Whh0 : (m == 1) ? Wih1 : Whh1;
    _Float16* dst = (m == 0) ? Whh0p : (m == 1) ? Wih1p : Whh1p;
    dst[p] = (_Float16)src[row*256 + col];
    return;
  } e -= 3*196608;
  if (e < 65536)  { float x = W1[e]; _Float16 h = (_Float16)x; W1h[e] = h; W1l[e] = (_Float16)(x - (float)h); return; } e -= 65536;
  if (e < 131072) { float x = W2[e]; _Float16 h = (_Float16)x; W2h[e] = h; W2l[e] = (_Float16)(x - (float)h); return; } e -= 131072;
  if (e < 196608) { int n = e >> 8, c = e & 255; float x = Wih0[n*291 + 35 + c]; _Float16 h = (_Float16)x; Wih0hh[e] = h; Wih0hl[e] = (_Float16)(x - (float)h); return; } e -= 196608;
  if (e < B*HDIM) { float x = hf[e]; _Float16 h = (_Float16)x; hfh[e] = h; hfl[e] = (_Float16)(x - (float)h); return; } e -= B*HDIM;
  if (e < KSTEPS*768) {
    int k = e / 768, n = e % 768;
    float pos = (float)k;
    const float fac = -9.210340371976184f / 31.0f;   // -ln(10000)/(TD-1)
    float acc = 0.0f;
    #pragma unroll
    for (int j = 0; j < 31; ++j) {
      int i = j >> 1;
      float ang = pos * expf((float)(2*i) * fac);
      float t = (j & 1) ? cosf(ang) : sinf(ang);
      acc += t * Wih0[n*291 + 3 + j];
    }
    acc += (pos / 30.0f) * Wih0[n*291 + 3 + 31];
    teW[e] = acc;
  }
}

// ------- XcT[n*B + r] = (hf @ Wih0[:,35:291].T)[r,n] + bih0[n]  (transposed, f32) -------
__global__ __launch_bounds__(64) void xc_kernel(
    const _Float16* __restrict__ hfh, const _Float16* __restrict__ hfl,
    const _Float16* __restrict__ Wh, const _Float16* __restrict__ Wl,
    const float* __restrict__ bih0, float* __restrict__ XcT, int B)
{
  int l = threadIdx.x, l15 = l & 15, l4 = l >> 4;
  int bm = blockIdx.x;
  int bn = blockIdx.y;
  f32x4 acc[4];
  #pragma unroll
  for (int i = 0; i < 4; ++i) acc[i] = (f32x4){0,0,0,0};
  const _Float16* ah = hfh + (size_t)(bm*16 + l15)*256 + l4*8;
  const _Float16* al = hfl + (size_t)(bm*16 + l15)*256 + l4*8;
  #pragma unroll
  for (int kk = 0; kk < 8; ++kk) {
    f16x8 aH = *(const f16x8*)(ah + kk*32);
    f16x8 aL = *(const f16x8*)(al + kk*32);
    #pragma unroll
    for (int i = 0; i < 4; ++i) {
      size_t boff = (size_t)(bn*64 + i*16 + l15)*256 + l4*8 + kk*32;
      f16x8 bH = *(const f16x8*)(Wh + boff);
      f16x8 bL = *(const f16x8*)(Wl + boff);
      acc[i] = mfma16(aH, bH, acc[i]);
      acc[i] = mfma16(aL, bH, acc[i]);
      acc[i] = mfma16(aH, bL, acc[i]);
    }
  }
  #pragma unroll
  for (int i = 0; i < 4; ++i) {
    int n = bn*64 + i*16 + l15;
    float bb = bih0[n];
    #pragma unroll
    for (int j = 0; j < 4; ++j) {
      int r = bm*16 + l4*4 + j;
      XcT[(size_t)n*B + r] = acc[i][j] + bb;
    }
  }
}

// ---------------- main persistent GRU kernel ----------------
// LDS map (bytes)
#define OFF_H0    0        // h0: hi 16KB, lo 16KB (in-place)
#define OFF_H1    32768
#define OFF_TMP   65536    // 32KB hmid temp (h_init only)
#define OFF_WS3   98304    // 768*3 f32
#define OFF_BHH0  107520
#define OFF_BI1   110592
#define OFF_BH1   113664
#define OFF_WOUT  116736
#define OFF_SPH   119808   // 32*8 f32
#define OFF_BOUT  120832
#define LDS_BYTES 120848

__global__ __launch_bounds__(NTHR) void gru_main(
    const float* __restrict__ istate,
    const float* __restrict__ b1g, const float* __restrict__ b2g,
    const float* __restrict__ Wih0, const float* __restrict__ bhh0g,
    const float* __restrict__ bih1g, const float* __restrict__ bhh1g,
    const float* __restrict__ Woutg, const float* __restrict__ boutg,
    const _Float16* __restrict__ Whh0p, const _Float16* __restrict__ Wih1p,
    const _Float16* __restrict__ Whh1p,
    const _Float16* __restrict__ W1h, const _Float16* __restrict__ W1l,
    const _Float16* __restrict__ W2h, const _Float16* __restrict__ W2l,
    const _Float16* __restrict__ hfh, const _Float16* __restrict__ hfl,
    const float* __restrict__ teW, const float* __restrict__ XcT,
    float* __restrict__ out, int B)
{
  extern __shared__ char smem[];
  char* h0H = smem + OFF_H0;  char* h0L = smem + OFF_H0 + 16384;
  char* h1H = smem + OFF_H1;  char* h1L = smem + OFF_H1 + 16384;
  float* Ws3   = (float*)(smem + OFF_WS3);
  float* bhh0L = (float*)(smem + OFF_BHH0);
  float* bi1L  = (float*)(smem + OFF_BI1);
  float* bh1L  = (float*)(smem + OFF_BH1);
  float* WoutL = (float*)(smem + OFF_WOUT);
  float* sph   = (float*)(smem + OFF_SPH);
  float* boutL = (float*)(smem + OFF_BOUT);

  const int tid = threadIdx.x;
  const int w = tid >> 6;
  const int lane = tid & 63;
  const int l15 = lane & 15;
  const int l4 = lane >> 4;
  const int l31 = lane & 31;
  const int l5 = lane >> 5;
  const int row0 = blockIdx.x * RPB;

  // ---- constants to LDS
  for (int i = tid; i < 2304; i += NTHR) Ws3[i] = Wih0[(i/3)*291 + (i%3)];
  for (int i = tid; i < 768; i += NTHR) {
    bhh0L[i] = bhh0g[i]; bi1L[i] = bih1g[i]; bh1L[i] = bhh1g[i]; WoutL[i] = Woutg[i];
  }
  if (tid < 3) boutL[tid] = boutg[tid];
  if (tid < RPB) {
    const float* is = istate + (size_t)(row0 + tid) * 3;
    float s0 = is[0], s1 = is[1], s2 = is[2];
    float* sp = sph + tid*8;
    sp[0] = s0; sp[1] = s1; sp[2] = s2;
    sp[3] = s0; sp[4] = s0; sp[5] = s0;
  }

  // ---- h_init GEMM1: relu(hf @ W1.T + b1) -> hmid (hi/lo) in TMP
  {
    char* mH = smem + OFF_TMP;
    char* mL = smem + OFF_TMP + 16384;
    #pragma unroll
    for (int i = 0; i < 2; ++i) {
      int nt = w*2 + i;
      f32x4 acc0 = {0,0,0,0}, acc1 = {0,0,0,0};
      const _Float16* brh = W1h + (nt*16 + l15)*256 + l4*8;
      const _Float16* brl = W1l + (nt*16 + l15)*256 + l4*8;
      const _Float16* a0h = hfh + (size_t)(row0 + l15)*256 + l4*8;
      const _Float16* a0l = hfl + (size_t)(row0 + l15)*256 + l4*8;
      #pragma unroll
      for (int kk = 0; kk < 8; ++kk) {
        f16x8 bH = *(const f16x8*)(brh + kk*32);
        f16x8 bL = *(const f16x8*)(brl + kk*32);
        f16x8 aH0 = *(const f16x8*)(a0h + kk*32);
        f16x8 aL0 = *(const f16x8*)(a0l + kk*32);
        f16x8 aH1 = *(const f16x8*)(a0h + 16*256 + kk*32);
        f16x8 aL1 = *(const f16x8*)(a0l + 16*256 + kk*32);
        acc0 = mfma16(aH0, bH, acc0); acc0 = mfma16(aL0, bH, acc0); acc0 = mfma16(aH0, bL, acc0);
        acc1 = mfma16(aH1, bH, acc1); acc1 = mfma16(aL1, bH, acc1); acc1 = mfma16(aH1, bL, acc1);
      }
      int n = nt*16 + l15;
      float bb = b1g[n];
      #pragma unroll
      for (int mt = 0; mt < 2; ++mt) {
        f32x4 acc = mt ? acc1 : acc0;
        #pragma unroll
        for (int j = 0; j < 4; ++j) {
          int r = mt*16 + l4*4 + j;
          float v = fmaxf(acc[j] + bb, 0.0f);
          wrsplit(mH, mL, swz(r, n), v);
        }
      }
    }
  }
  __syncthreads();

  // ---- h_init GEMM2: tanh(hmid @ W2.T + b2) -> h0 / h1 (hi/lo)
  {
    const char* mH = smem + OFF_TMP;
    const char* mL = smem + OFF_TMP + 16384;
    #pragma unroll
    for (int i = 0; i < 4; ++i) {
      int nt = w*4 + i;
      f32x4 acc0 = {0,0,0,0}, acc1 = {0,0,0,0};
      const _Float16* brh = W2h + (nt*16 + l15)*256 + l4*8;
      const _Float16* brl = W2l + (nt*16 + l15)*256 + l4*8;
      #pragma unroll
      for (int kk = 0; kk < 8; ++kk) {
        int kc = kk*32 + l4*8;
        f16x8 bH = *(const f16x8*)(brh + kk*32);
        f16x8 bL = *(const f16x8*)(brl + kk*32);
        f16x8 aH0 = *(const f16x8*)(mH + swz(l15, kc));
        f16x8 aL0 = *(const f16x8*)(mL + swz(l15, kc));
        f16x8 aH1 = *(const f16x8*)(mH + swz(16 + l15, kc));
        f16x8 aL1 = *(const f16x8*)(mL + swz(16 + l15, kc));
        acc0 = mfma16(aH0, bH, acc0); acc0 = mfma16(aL0, bH, acc0); acc0 = mfma16(aH0, bL, acc0);
        acc1 = mfma16(aH1, bH, acc1); acc1 = mfma16(aL1, bH, acc1); acc1 = mfma16(aH1, bL, acc1);
      }
      int n = nt*16 + l15;
      float bb = b2g[n];
      #pragma unroll
      for (int mt = 0; mt < 2; ++mt) {
        f32x4 acc = mt ? acc1 : acc0;
        #pragma unroll
        for (int j = 0; j < 4; ++j) {
          int r = mt*16 + l4*4 + j;
          float v = ftanh(acc[j] + bb);
          if (n < 256) wrsplit(h0H, h0L, swz(r, n), v);
          else         wrsplit(h1H, h1L, swz(r, n - 256), v);
        }
      }
    }
  }
  __syncthreads();

  const size_t outP = (size_t)B * KSTEPS;
  const int hcol = w*32 + l31;           // this thread's output column (per gate)

  // per-wave packed-weight bases (stride: tile 1536 elems, gate 512)
  const _Float16* wpB  = Whh0p + (size_t)w*24576 + lane*8;
  const _Float16* wpH1 = Whh1p + (size_t)w*24576 + lane*8;
  const _Float16* wpI1 = Wih1p + (size_t)w*24576 + lane*8;

  for (int k = 0; k < KSTEPS; ++k) {
    const float* teWk = teW + k*768;

    // ================= Phase B: gh0 = h0 @ Whh0.T (regs, dist-1 prefetch) ===
    f32x16 cR = ZV16, cZ = ZV16, cN = ZV16;
    {
      f16x8 wR = *(const f16x8*)(wpB);
      f16x8 wZ = *(const f16x8*)(wpB + 512);
      f16x8 wN = *(const f16x8*)(wpB + 1024);
      for (int t = 0; t < 16; ++t) {
        f16x8 nR, nZ, nN;
        if (t < 15) {
          const _Float16* np = wpB + (t+1)*1536;
          nR = *(const f16x8*)(np);
          nZ = *(const f16x8*)(np + 512);
          nN = *(const f16x8*)(np + 1024);
        }
        int aoff = swz(l31, t*16 + l5*8);
        f16x8 aH = *(const f16x8*)(h0H + aoff);
        f16x8 aL = *(const f16x8*)(h0L + aoff);
        cR = mfma32(aH, wR, cR); cR = mfma32(aL, wR, cR);
        cZ = mfma32(aH, wZ, cZ); cZ = mfma32(aL, wZ, cZ);
        cN = mfma32(aH, wN, cN); cN = mfma32(aL, wN, cN);
        if (t < 15) { wR = nR; wZ = nZ; wN = nN; }
      }
    }
    __syncthreads();   // all waves done reading h0_old

    // ---- GRU-0 epilogue, in-place h0 update (XcT via non-temporal loads)
    {
      float teR = teWk[hcol], teZ = teWk[256 + hcol], teN = teWk[512 + hcol];
      float wR0 = Ws3[hcol*3+0],       wR1 = Ws3[hcol*3+1],       wR2 = Ws3[hcol*3+2];
      float wZ0 = Ws3[(hcol+256)*3+0], wZ1 = Ws3[(hcol+256)*3+1], wZ2 = Ws3[(hcol+256)*3+2];
      float wN0 = Ws3[(hcol+512)*3+0], wN1 = Ws3[(hcol+512)*3+1], wN2 = Ws3[(hcol+512)*3+2];
      float bhR = bhh0L[hcol], bhZ = bhh0L[256 + hcol], bhN = bhh0L[512 + hcol];
      #pragma unroll
      for (int q = 0; q < 4; ++q) {
        int rbase = q*8 + l5*4;
        f32x4 xcR = __builtin_nontemporal_load((const f32x4*)(XcT + (size_t)hcol*B + row0 + rbase));
        f32x4 xcZ = __builtin_nontemporal_load((const f32x4*)(XcT + (size_t)(256 + hcol)*B + row0 + rbase));
        f32x4 xcN = __builtin_nontemporal_load((const f32x4*)(XcT + (size_t)(512 + hcol)*B + row0 + rbase));
        #pragma unroll
        for (int j = 0; j < 4; ++j) {
          int reg = q*4 + j;
          int r = rbase + j;
          const float* sp = sph + r*8;
          float s0 = sp[0], s1 = sp[1], s2 = sp[2];
          float giR = xcR[j] + teR + s0*wR0 + s1*wR1 + s2*wR2;
          float giZ = xcZ[j] + teZ + s0*wZ0 + s1*wZ1 + s2*wZ2;
          float giN = xcN[j] + teN + s0*wN0 + s1*wN1 + s2*wN2;
          float rg = fsigm(giR + cR[reg] + bhR);
          float zg = fsigm(giZ + cZ[reg] + bhZ);
          float ng = ftanh(giN + rg * (cN[reg] + bhN));
          float hold = rdpair(h0H, h0L, swz(r, hcol));
          float hnew = (1.0f - zg) * ng + zg * hold;
          wrsplit(h0H, h0L, swz(r, hcol), hnew);
        }
      }
    }
    __syncthreads();   // h0_new visible to all

    // ===== Phase AC: K=512 concat GEMM [h1_old; h0_new] @ [Whh1; Wih1].T ====
    // R/Z merged accumulators; N split (hNa from Whh1, iNa from Wih1)
    f32x16 aRa = ZV16, aZa = ZV16, hNa = ZV16, iNa = ZV16;
    {
      f16x8 wR = *(const f16x8*)(wpH1);
      f16x8 wZ = *(const f16x8*)(wpH1 + 512);
      f16x8 wN = *(const f16x8*)(wpH1 + 1024);
      // sub0: h1_old x Whh1 (t=15 prefetches sub1's first tile)
      for (int t = 0; t < 16; ++t) {
        const _Float16* np = (t < 15) ? (wpH1 + (t+1)*1536) : wpI1;
        f16x8 nR = *(const f16x8*)(np);
        f16x8 nZ = *(const f16x8*)(np + 512);
        f16x8 nN = *(const f16x8*)(np + 1024);
        int aoff = swz(l31, t*16 + l5*8);
        f16x8 aH = *(const f16x8*)(h1H + aoff);
        f16x8 aL = *(const f16x8*)(h1L + aoff);
        aRa = mfma32(aH, wR, aRa); aRa = mfma32(aL, wR, aRa);
        aZa = mfma32(aH, wZ, aZa); aZa = mfma32(aL, wZ, aZa);
        hNa = mfma32(aH, wN, hNa); hNa = mfma32(aL, wN, hNa);
        wR = nR; wZ = nZ; wN = nN;
      }
      // sub1: h0_new x Wih1
      for (int t = 0; t < 16; ++t) {
        f16x8 nR, nZ, nN;
        if (t < 15) {
          const _Float16* np = wpI1 + (t+1)*1536;
          nR = *(const f16x8*)(np);
          nZ = *(const f16x8*)(np + 512);
          nN = *(const f16x8*)(np + 1024);
        }
        int aoff = swz(l31, t*16 + l5*8);
        f16x8 aH = *(const f16x8*)(h0H + aoff);
        f16x8 aL = *(const f16x8*)(h0L + aoff);
        aRa = mfma32(aH, wR, aRa); aRa = mfma32(aL, wR, aRa);
        aZa = mfma32(aH, wZ, aZa); aZa = mfma32(aL, wZ, aZa);
        iNa = mfma32(aH, wN, iNa); iNa = mfma32(aL, wN, iNa);
        if (t < 15) { wR = nR; wZ = nZ; wN = nN; }
      }
    }
    __syncthreads();   // all waves done reading h1_old

    // ---- GRU-1 epilogue, in-place h1 update
    {
      float biR = bi1L[hcol], biZ = bi1L[256+hcol], biN = bi1L[512+hcol];
      float bhRb = bh1L[hcol], bhZb = bh1L[256+hcol], bhNb = bh1L[512+hcol];
      #pragma unroll
      for (int q = 0; q < 4; ++q) {
        int rbase = q*8 + l5*4;
        #pragma unroll
        for (int j = 0; j < 4; ++j) {
          int reg = q*4 + j;
          int r = rbase + j;
          float rg = fsigm(aRa[reg] + biR + bhRb);
          float zg = fsigm(aZa[reg] + biZ + bhZb);
          float ng = ftanh(iNa[reg] + biN + rg * (hNa[reg] + bhNb));
          float hold = rdpair(h1H, h1L, swz(r, hcol));
          float hnew = (1.0f - zg) * ng + zg * hold;
          wrsplit(h1H, h1L, swz(r, hcol), hnew);
        }
      }
    }
    __syncthreads();   // h1_new visible

    // ---- Phase D: qr = h1n @ Wout.T + bout, quantiles, state update
    {
      int r = tid >> 4, li = tid & 15;
      float q0 = 0.0f, q1 = 0.0f, q2 = 0.0f;
      #pragma unroll
      for (int i = 0; i < 16; ++i) {
        int h = li + i*16;
        float v = rdpair(h1H, h1L, swz(r, h));
        q0 += v * WoutL[h];
        q1 += v * WoutL[256 + h];
        q2 += v * WoutL[512 + h];
      }
      #pragma unroll
      for (int m = 1; m < 16; m <<= 1) {
        q0 += __shfl_xor(q0, m);
        q1 += __shfl_xor(q1, m);
        q2 += __shfl_xor(q2, m);
      }
      if (li == 0) {
        float qlo = q0 + boutL[0];
        float qm  = qlo + softplusf(q1 + boutL[1] - qlo);
        float qhi = qm  + softplusf(q2 + boutL[2] - qm);
        size_t b = row0 + r;
        out[b*KSTEPS + k]            = qlo;
        out[outP + b*KSTEPS + k]     = qm;
        out[2*outP + b*KSTEPS + k]   = qhi;
        float* sp = sph + r*8;
        float p1 = sp[4], p2 = sp[5];
        sp[0] = qm;
        sp[1] = (qm - p1) * 5.0f;
        sp[2] = (qm - 2.0f*p2 + p1) * 100.0f;
        sp[3] = p1; sp[4] = p2; sp[5] = qm;
      }
    }
    // no barrier needed before next step's B K-loop (reads only h0 + weights;
    // first sph/h1 consumers are >=1 barrier away)
  }
}

extern "C" void kernel_launch(void* const* d_in, const int* in_sizes, int n_in,
                              void* d_out, int out_size, void* d_ws, size_t ws_size,
                              hipStream_t stream) {
  const float* hf     = (const float*)d_in[0];
  const float* istate = (const float*)d_in[1];
  const float* W1     = (const float*)d_in[2];
  const float* b1     = (const float*)d_in[3];
  const float* W2     = (const float*)d_in[4];
  const float* b2     = (const float*)d_in[5];
  const float* Wih0   = (const float*)d_in[6];
  const float* Whh0   = (const float*)d_in[7];
  const float* bih0   = (const float*)d_in[8];
  const float* bhh0   = (const float*)d_in[9];
  const float* Wih1   = (const float*)d_in[10];
  const float* Whh1   = (const float*)d_in[11];
  const float* bih1   = (const float*)d_in[12];
  const float* bhh1   = (const float*)d_in[13];
  const float* Wout   = (const float*)d_in[14];
  const float* bout   = (const float*)d_in[15];
  float* out = (float*)d_out;
  const int B = in_sizes[0] / HDIM;   // 4096

  char* ws = (char*)d_ws;
  size_t o = 0;
  _Float16* Whh0p  = (_Float16*)(ws + o); o += 393216;
  _Float16* Wih1p  = (_Float16*)(ws + o); o += 393216;
  _Float16* Whh1p  = (_Float16*)(ws + o); o += 393216;
  _Float16* W1h    = (_Float16*)(ws + o); o += 131072;
  _Float16* W1l    = (_Float16*)(ws + o); o += 131072;
  _Float16* W2h    = (_Float16*)(ws + o); o += 262144;
  _Float16* W2l    = (_Float16*)(ws + o); o += 262144;
  _Float16* Wih0hh = (_Float16*)(ws + o); o += 393216;
  _Float16* Wih0hl = (_Float16*)(ws + o); o += 393216;
  _Float16* hfh    = (_Float16*)(ws + o); o += (size_t)B * HDIM * 2;
  _Float16* hfl    = (_Float16*)(ws + o); o += (size_t)B * HDIM * 2;
  float*    teW    = (float*)(ws + o);    o += (size_t)KSTEPS * 768 * 4;
  float*    XcT    = (float*)(ws + o);    o += (size_t)B * 768 * 4;
  if (ws_size < o) return;

  const int prep_total = 196608*3 + 65536 + 131072 + 196608 + B*HDIM + KSTEPS*768;
  prep_kernel<<<dim3((prep_total + 255) / 256), dim3(256), 0, stream>>>(
      W1, W2, Wih0, Whh0, Wih1, Whh1, hf,
      Whh0p, Wih1p, Whh1p, W1h, W1l, W2h, W2l, Wih0hh, Wih0hl, hfh, hfl, teW, B);

  xc_kernel<<<dim3(B/16, 12), dim3(64), 0, stream>>>(hfh, hfl, Wih0hh, Wih0hl, bih0, XcT, B);

  hipFuncSetAttribute((const void*)gru_main,
                      hipFuncAttributeMaxDynamicSharedMemorySize, LDS_BYTES);
  gru_main<<<dim3(B/RPB), dim3(NTHR), LDS_BYTES, stream>>>(
      istate, b1, b2, Wih0, bhh0, bih1, bhh1, Wout, bout,
      Whh0p, Wih1p, Whh1p, W1h, W1l, W2h, W2l, hfh, hfl, teW, XcT, out, B);
}

// Round 9
// 905.351 us; speedup vs baseline: 2.0477x; 2.0477x over previous
//
#include <hip/hip_runtime.h>

#define HDIM 256
#define KSTEPS 30
#define RPB 32            // rows per block
#define NTHR 512          // 8 waves

typedef _Float16 f16x8 __attribute__((ext_vector_type(8)));
typedef float f32x4 __attribute__((ext_vector_type(4)));
typedef float f32x16 __attribute__((ext_vector_type(16)));

#define ZV16 (f32x16){0,0,0,0,0,0,0,0,0,0,0,0,0,0,0,0}

__device__ __forceinline__ f32x4 mfma16(f16x8 a, f16x8 b, f32x4 c) {
  return __builtin_amdgcn_mfma_f32_16x16x32_f16(a, b, c, 0, 0, 0);
}
__device__ __forceinline__ f32x16 mfma32(f16x8 a, f16x8 b, f32x16 c) {
  return __builtin_amdgcn_mfma_f32_32x32x16_f16(a, b, c, 0, 0, 0);
}

// fast transcendentals via v_exp_f32 / v_rcp_f32 (~2 ULP; threshold 0.037)
__device__ __forceinline__ float fsigm(float x) {
  return __builtin_amdgcn_rcpf(1.0f + __expf(-x));
}
__device__ __forceinline__ float ftanh(float x) {
  float t = __expf(2.0f * x);                 // inf for big x -> rcp=0 -> 1
  return 1.0f - 2.0f * __builtin_amdgcn_rcpf(t + 1.0f);
}
__device__ __forceinline__ float softplusf(float x) {
  return fmaxf(x, 0.0f) + log1pf(__expf(-fabsf(x)));
}

// swizzled byte offset for a [32][256] fp16 LDS tile (row stride 512B)
__device__ __forceinline__ int swz(int r, int c) {
  return r * 512 + ((c * 2) ^ ((r & 7) << 4));
}

__device__ __forceinline__ void wrsplit(char* hi, char* lo, int off, float v) {
  _Float16 h = (_Float16)v;
  *(_Float16*)(hi + off) = h;
  *(_Float16*)(lo + off) = (_Float16)(v - (float)h);
}
__device__ __forceinline__ float rdpair(const char* hi, const char* lo, int off) {
  return (float)*(const _Float16*)(hi + off) + (float)*(const _Float16*)(lo + off);
}

// async global->LDS, 16B per lane; dest = ldsbase + lane*16 (linear)
__device__ __forceinline__ void glds16(const _Float16* src, char* lds) {
  __builtin_amdgcn_global_load_lds(
      (const __attribute__((address_space(1))) unsigned int*)src,
      (__attribute__((address_space(3))) unsigned int*)lds, 16, 0, 0);
}

// stage one k16-tile (3 gates, 1KB each, packed contiguous) into a slab buffer
// wp is per-lane: packed wave base + lane*8
#define STAGE3(wp, idx, dst) do {                            \
  const _Float16* _s = (wp) + (idx)*1536;                    \
  glds16(_s, (dst));                                         \
  glds16(_s + 512, (dst) + 1024);                            \
  glds16(_s + 1024, (dst) + 2048);                           \
} while (0)

#define WAITV(n) do { asm volatile("s_waitcnt vmcnt(" #n ")"); \
  __builtin_amdgcn_sched_barrier(0); } while (0)

#define ROT() do { char* _t = bA; bA = bB; bB = bC; bC = _t; } while (0)

// ---------------- prep: conversions + MFMA-order weight packing + teW ----------------
// Packed recurrent-weight layout (fp16):
//   e = (((w*16 + t)*3 + g)*64 + lane)*8 + j
//   src row = w*32 + (lane&31) + g*256 ; src col = t*16 + (lane>>5)*8 + j
// After glds16 staging (linear lane*16 dest), lane l's mfma32 B-fragment for
// (tile t, gate g) sits exactly at slab + g*1024 + l*16 -> conflict-free read.
__global__ __launch_bounds__(256) void prep_kernel(
    const float* __restrict__ W1, const float* __restrict__ W2,
    const float* __restrict__ Wih0, const float* __restrict__ Whh0,
    const float* __restrict__ Wih1, const float* __restrict__ Whh1,
    const float* __restrict__ hf,
    _Float16* __restrict__ Whh0p, _Float16* __restrict__ Wih1p,
    _Float16* __restrict__ Whh1p,
    _Float16* __restrict__ W1h, _Float16* __restrict__ W1l,
    _Float16* __restrict__ W2h, _Float16* __restrict__ W2l,
    _Float16* __restrict__ Wih0hh, _Float16* __restrict__ Wih0hl,
    _Float16* __restrict__ hfh, _Float16* __restrict__ hfl,
    float* __restrict__ teW, int B)
{
  int e = blockIdx.x * 256 + threadIdx.x;
  if (e < 3*196608) {
    int m = e / 196608, p = e % 196608;
    int j = p & 7, lane = (p >> 3) & 63;
    int q = p >> 9;
    int g = q % 3, tt = q / 3;
    int t = tt & 15, wv = tt >> 4;
    int row = wv*32 + (lane & 31) + g*256;
    int col = t*16 + (lane >> 5)*8 + j;
    const float* src = (m == 0) ? Whh0 : (m == 1) ? Wih1 : Whh1;
    _Float16* dst = (m == 0) ? Whh0p : (m == 1) ? Wih1p : Whh1p;
    dst[p] = (_Float16)src[row*256 + col];
    return;
  } e -= 3*196608;
  if (e < 65536)  { float x = W1[e]; _Float16 h = (_Float16)x; W1h[e] = h; W1l[e] = (_Float16)(x - (float)h); return; } e -= 65536;
  if (e < 131072) { float x = W2[e]; _Float16 h = (_Float16)x; W2h[e] = h; W2l[e] = (_Float16)(x - (float)h); return; } e -= 131072;
  if (e < 196608) { int n = e >> 8, c = e & 255; float x = Wih0[n*291 + 35 + c]; _Float16 h = (_Float16)x; Wih0hh[e] = h; Wih0hl[e] = (_Float16)(x - (float)h); return; } e -= 196608;
  if (e < B*HDIM) { float x = hf[e]; _Float16 h = (_Float16)x; hfh[e] = h; hfl[e] = (_Float16)(x - (float)h); return; } e -= B*HDIM;
  if (e < KSTEPS*768) {
    int k = e / 768, n = e % 768;
    float pos = (float)k;
    const float fac = -9.210340371976184f / 31.0f;   // -ln(10000)/(TD-1)
    float acc = 0.0f;
    #pragma unroll
    for (int j = 0; j < 31; ++j) {
      int i = j >> 1;
      float ang = pos * expf((float)(2*i) * fac);
      float t = (j & 1) ? cosf(ang) : sinf(ang);
      acc += t * Wih0[n*291 + 3 + j];
    }
    acc += (pos / 30.0f) * Wih0[n*291 + 3 + 31];
    teW[e] = acc;
  }
}

// ------- XcT[n*B + r] = (hf @ Wih0[:,35:291].T)[r,n] + bih0[n]  (transposed, f32) -------
__global__ __launch_bounds__(64) void xc_kernel(
    const _Float16* __restrict__ hfh, const _Float16* __restrict__ hfl,
    const _Float16* __restrict__ Wh, const _Float16* __restrict__ Wl,
    const float* __restrict__ bih0, float* __restrict__ XcT, int B)
{
  int l = threadIdx.x, l15 = l & 15, l4 = l >> 4;
  int bm = blockIdx.x;
  int bn = blockIdx.y;
  f32x4 acc[4];
  #pragma unroll
  for (int i = 0; i < 4; ++i) acc[i] = (f32x4){0,0,0,0};
  const _Float16* ah = hfh + (size_t)(bm*16 + l15)*256 + l4*8;
  const _Float16* al = hfl + (size_t)(bm*16 + l15)*256 + l4*8;
  #pragma unroll
  for (int kk = 0; kk < 8; ++kk) {
    f16x8 aH = *(const f16x8*)(ah + kk*32);
    f16x8 aL = *(const f16x8*)(al + kk*32);
    #pragma unroll
    for (int i = 0; i < 4; ++i) {
      size_t boff = (size_t)(bn*64 + i*16 + l15)*256 + l4*8 + kk*32;
      f16x8 bH = *(const f16x8*)(Wh + boff);
      f16x8 bL = *(const f16x8*)(Wl + boff);
      acc[i] = mfma16(aH, bH, acc[i]);
      acc[i] = mfma16(aL, bH, acc[i]);
      acc[i] = mfma16(aH, bL, acc[i]);
    }
  }
  #pragma unroll
  for (int i = 0; i < 4; ++i) {
    int n = bn*64 + i*16 + l15;
    float bb = bih0[n];
    #pragma unroll
    for (int j = 0; j < 4; ++j) {
      int r = bm*16 + l4*4 + j;
      XcT[(size_t)n*B + r] = acc[i][j] + bb;
    }
  }
}

// ---------------- main persistent GRU kernel ----------------
// LDS map (bytes) — identical to R7 (proven no-spill at VGPR 116)
#define OFF_H0    0        // h0: hi 16KB, lo 16KB (in-place)
#define OFF_H1    32768
#define OFF_W     65536    // slab: 3 bufs x 24KB; [buf][wave 3KB][gate 1KB]
                           // (also hmid hi/lo temp during h_init)
#define OFF_WS3   139264   // 768*3 f32
#define OFF_BHH0  148480
#define OFF_BI1   151552
#define OFF_BH1   154624
#define OFF_WOUT  157696
#define OFF_SPH   160768   // 32*8 f32
#define OFF_BOUT  161792
#define LDS_BYTES 161808   // <= 163840

__global__ __launch_bounds__(NTHR) void gru_main(
    const float* __restrict__ istate,
    const float* __restrict__ b1g, const float* __restrict__ b2g,
    const float* __restrict__ Wih0, const float* __restrict__ bhh0g,
    const float* __restrict__ bih1g, const float* __restrict__ bhh1g,
    const float* __restrict__ Woutg, const float* __restrict__ boutg,
    const _Float16* __restrict__ Whh0p, const _Float16* __restrict__ Wih1p,
    const _Float16* __restrict__ Whh1p,
    const _Float16* __restrict__ W1h, const _Float16* __restrict__ W1l,
    const _Float16* __restrict__ W2h, const _Float16* __restrict__ W2l,
    const _Float16* __restrict__ hfh, const _Float16* __restrict__ hfl,
    const float* __restrict__ teW, const float* __restrict__ XcT,
    float* __restrict__ out, int B)
{
  extern __shared__ char smem[];
  char* h0H = smem + OFF_H0;  char* h0L = smem + OFF_H0 + 16384;
  char* h1H = smem + OFF_H1;  char* h1L = smem + OFF_H1 + 16384;
  float* Ws3   = (float*)(smem + OFF_WS3);
  float* bhh0L = (float*)(smem + OFF_BHH0);
  float* bi1L  = (float*)(smem + OFF_BI1);
  float* bh1L  = (float*)(smem + OFF_BH1);
  float* WoutL = (float*)(smem + OFF_WOUT);
  float* sph   = (float*)(smem + OFF_SPH);
  float* boutL = (float*)(smem + OFF_BOUT);

  const int tid = threadIdx.x;
  const int w = tid >> 6;
  const int lane = tid & 63;
  const int l15 = lane & 15;
  const int l4 = lane >> 4;
  const int l31 = lane & 31;
  const int l5 = lane >> 5;
  const int row0 = blockIdx.x * RPB;

  // wave-uniform slab bases (per-wave private 3KB region in each of 3 buffers)
  const int wsb = __builtin_amdgcn_readfirstlane(OFF_W + w * 3072);
  char* sl0 = smem + wsb;
  char* sl1 = sl0 + 24576;
  char* sl2 = sl1 + 24576;

  // per-lane packed-weight bases (tile stride 1536 elems, gate stride 512)
  const _Float16* wpB  = Whh0p + (size_t)w*24576 + lane*8;
  const _Float16* wpH1 = Whh1p + (size_t)w*24576 + lane*8;
  const _Float16* wpI1 = Wih1p + (size_t)w*24576 + lane*8;

  // ---- constants to LDS
  for (int i = tid; i < 2304; i += NTHR) Ws3[i] = Wih0[(i/3)*291 + (i%3)];
  for (int i = tid; i < 768; i += NTHR) {
    bhh0L[i] = bhh0g[i]; bi1L[i] = bih1g[i]; bh1L[i] = bhh1g[i]; WoutL[i] = Woutg[i];
  }
  if (tid < 3) boutL[tid] = boutg[tid];
  if (tid < RPB) {
    const float* is = istate + (size_t)(row0 + tid) * 3;
    float s0 = is[0], s1 = is[1], s2 = is[2];
    float* sp = sph + tid*8;
    sp[0] = s0; sp[1] = s1; sp[2] = s2;
    sp[3] = s0; sp[4] = s0; sp[5] = s0;
  }

  // ---- h_init GEMM1: relu(hf @ W1.T + b1) -> hmid (hi/lo) in slab region
  {
    char* mH = smem + OFF_W;
    char* mL = smem + OFF_W + 16384;
    #pragma unroll
    for (int i = 0; i < 2; ++i) {
      int nt = w*2 + i;
      f32x4 acc0 = {0,0,0,0}, acc1 = {0,0,0,0};
      const _Float16* brh = W1h + (nt*16 + l15)*256 + l4*8;
      const _Float16* brl = W1l + (nt*16 + l15)*256 + l4*8;
      const _Float16* a0h = hfh + (size_t)(row0 + l15)*256 + l4*8;
      const _Float16* a0l = hfl + (size_t)(row0 + l15)*256 + l4*8;
      #pragma unroll
      for (int kk = 0; kk < 8; ++kk) {
        f16x8 bH = *(const f16x8*)(brh + kk*32);
        f16x8 bL = *(const f16x8*)(brl + kk*32);
        f16x8 aH0 = *(const f16x8*)(a0h + kk*32);
        f16x8 aL0 = *(const f16x8*)(a0l + kk*32);
        f16x8 aH1 = *(const f16x8*)(a0h + 16*256 + kk*32);
        f16x8 aL1 = *(const f16x8*)(a0l + 16*256 + kk*32);
        acc0 = mfma16(aH0, bH, acc0); acc0 = mfma16(aL0, bH, acc0); acc0 = mfma16(aH0, bL, acc0);
        acc1 = mfma16(aH1, bH, acc1); acc1 = mfma16(aL1, bH, acc1); acc1 = mfma16(aH1, bL, acc1);
      }
      int n = nt*16 + l15;
      float bb = b1g[n];
      #pragma unroll
      for (int mt = 0; mt < 2; ++mt) {
        f32x4 acc = mt ? acc1 : acc0;
        #pragma unroll
        for (int j = 0; j < 4; ++j) {
          int r = mt*16 + l4*4 + j;
          float v = fmaxf(acc[j] + bb, 0.0f);
          wrsplit(mH, mL, swz(r, n), v);
        }
      }
    }
  }
  __syncthreads();

  // ---- h_init GEMM2: tanh(hmid @ W2.T + b2) -> h0 / h1 (hi/lo)
  {
    const char* mH = smem + OFF_W;
    const char* mL = smem + OFF_W + 16384;
    #pragma unroll
    for (int i = 0; i < 4; ++i) {
      int nt = w*4 + i;
      f32x4 acc0 = {0,0,0,0}, acc1 = {0,0,0,0};
      const _Float16* brh = W2h + (nt*16 + l15)*256 + l4*8;
      const _Float16* brl = W2l + (nt*16 + l15)*256 + l4*8;
      #pragma unroll
      for (int kk = 0; kk < 8; ++kk) {
        int kc = kk*32 + l4*8;
        f16x8 bH = *(const f16x8*)(brh + kk*32);
        f16x8 bL = *(const f16x8*)(brl + kk*32);
        f16x8 aH0 = *(const f16x8*)(mH + swz(l15, kc));
        f16x8 aL0 = *(const f16x8*)(mL + swz(l15, kc));
        f16x8 aH1 = *(const f16x8*)(mH + swz(16 + l15, kc));
        f16x8 aL1 = *(const f16x8*)(mL + swz(16 + l15, kc));
        acc0 = mfma16(aH0, bH, acc0); acc0 = mfma16(aL0, bH, acc0); acc0 = mfma16(aH0, bL, acc0);
        acc1 = mfma16(aH1, bH, acc1); acc1 = mfma16(aL1, bH, acc1); acc1 = mfma16(aH1, bL, acc1);
      }
      int n = nt*16 + l15;
      float bb = b2g[n];
      #pragma unroll
      for (int mt = 0; mt < 2; ++mt) {
        f32x4 acc = mt ? acc1 : acc0;
        #pragma unroll
        for (int j = 0; j < 4; ++j) {
          int r = mt*16 + l4*4 + j;
          float v = ftanh(acc[j] + bb);
          if (n < 256) wrsplit(h0H, h0L, swz(r, n), v);
          else         wrsplit(h1H, h1L, swz(r, n - 256), v);
        }
      }
    }
  }
  __syncthreads();

  const size_t outP = (size_t)B * KSTEPS;
  const int hcol = w*32 + l31;           // this thread's output column (per gate)
  const int boff = lane * 16;            // packed slab B-frag offset: conflict-free

  for (int k = 0; k < KSTEPS; ++k) {
    const float* teWk = teW + k*768;

    // ================= Phase B: gh0 = h0 @ Whh0.T (rolled, 3-buf, dist-2) ===
    f32x16 cR = ZV16, cZ = ZV16, cN = ZV16;
    {
      char *bA = sl0, *bB = sl1, *bC = sl2;
      STAGE3(wpB, 0, bA);
      STAGE3(wpB, 1, bB);
      #define BBODY(buf, kk) do {                                   \
        f16x8 bR = *(const f16x8*)((buf) + boff);                   \
        f16x8 bZ = *(const f16x8*)((buf) + 1024 + boff);            \
        f16x8 bN = *(const f16x8*)((buf) + 2048 + boff);            \
        int aoff = swz(l31, (kk)*16 + l5*8);                        \
        f16x8 aH = *(const f16x8*)(h0H + aoff);                     \
        f16x8 aL = *(const f16x8*)(h0L + aoff);                     \
        cR = mfma32(aH, bR, cR); cR = mfma32(aL, bR, cR);           \
        cZ = mfma32(aH, bZ, cZ); cZ = mfma32(aL, bZ, cZ);           \
        cN = mfma32(aH, bN, cN); cN = mfma32(aL, bN, cN);           \
      } while (0)
      for (int k16 = 0; k16 < 14; ++k16) {
        STAGE3(wpB, k16 + 2, bC);
        WAITV(6);
        BBODY(bA, k16);
        ROT();
      }
      WAITV(3); BBODY(bA, 14); ROT();
      WAITV(0); BBODY(bA, 15);
      #undef BBODY
    }
    __syncthreads();   // all waves done reading h0_old

    // ---- GRU-0 epilogue, in-place h0 update (XcT via non-temporal loads)
    {
      float teR = teWk[hcol], teZ = teWk[256 + hcol], teN = teWk[512 + hcol];
      float wR0 = Ws3[hcol*3+0],       wR1 = Ws3[hcol*3+1],       wR2 = Ws3[hcol*3+2];
      float wZ0 = Ws3[(hcol+256)*3+0], wZ1 = Ws3[(hcol+256)*3+1], wZ2 = Ws3[(hcol+256)*3+2];
      float wN0 = Ws3[(hcol+512)*3+0], wN1 = Ws3[(hcol+512)*3+1], wN2 = Ws3[(hcol+512)*3+2];
      float bhR = bhh0L[hcol], bhZ = bhh0L[256 + hcol], bhN = bhh0L[512 + hcol];
      #pragma unroll
      for (int q = 0; q < 4; ++q) {
        int rbase = q*8 + l5*4;
        f32x4 xcR = __builtin_nontemporal_load((const f32x4*)(XcT + (size_t)hcol*B + row0 + rbase));
        f32x4 xcZ = __builtin_nontemporal_load((const f32x4*)(XcT + (size_t)(256 + hcol)*B + row0 + rbase));
        f32x4 xcN = __builtin_nontemporal_load((const f32x4*)(XcT + (size_t)(512 + hcol)*B + row0 + rbase));
        #pragma unroll
        for (int j = 0; j < 4; ++j) {
          int reg = q*4 + j;
          int r = rbase + j;
          const float* sp = sph + r*8;
          float s0 = sp[0], s1 = sp[1], s2 = sp[2];
          float giR = xcR[j] + teR + s0*wR0 + s1*wR1 + s2*wR2;
          float giZ = xcZ[j] + teZ + s0*wZ0 + s1*wZ1 + s2*wZ2;
          float giN = xcN[j] + teN + s0*wN0 + s1*wN1 + s2*wN2;
          float rg = fsigm(giR + cR[reg] + bhR);
          float zg = fsigm(giZ + cZ[reg] + bhZ);
          float ng = ftanh(giN + rg * (cN[reg] + bhN));
          float hold = rdpair(h0H, h0L, swz(r, hcol));
          float hnew = (1.0f - zg) * ng + zg * hold;
          wrsplit(h0H, h0L, swz(r, hcol), hnew);
        }
      }
    }
    __syncthreads();   // h0_new visible to all

    // ===== Phase AC: K=512 concat GEMM [h1_old; h0_new] @ [Whh1; Wih1].T ====
    f32x16 aRa = ZV16, aZa = ZV16, hNa = ZV16, iNa = ZV16;
    {
      char *bA = sl0, *bB = sl1, *bC = sl2;
      STAGE3(wpH1, 0, bA);
      STAGE3(wpH1, 1, bB);
      #define ACBODY(buf, kk, AH, AL, ACN) do {                     \
        f16x8 bR = *(const f16x8*)((buf) + boff);                   \
        f16x8 bZ = *(const f16x8*)((buf) + 1024 + boff);            \
        f16x8 bN = *(const f16x8*)((buf) + 2048 + boff);            \
        int aoff = swz(l31, (kk)*16 + l5*8);                        \
        f16x8 aH = *(const f16x8*)((AH) + aoff);                    \
        f16x8 aL = *(const f16x8*)((AL) + aoff);                    \
        aRa = mfma32(aH, bR, aRa); aRa = mfma32(aL, bR, aRa);       \
        aZa = mfma32(aH, bZ, aZa); aZa = mfma32(aL, bZ, aZa);       \
        ACN = mfma32(aH, bN, ACN); ACN = mfma32(aL, bN, ACN);       \
      } while (0)
      // sub0: h1_old x Whh1 (stages cross into sub1's source near the end)
      for (int i = 0; i < 16; ++i) {
        const _Float16* sb = (i + 2 < 16) ? wpH1 : wpI1;
        STAGE3(sb, (i + 2) & 15, bC);
        WAITV(6);
        ACBODY(bA, i, h1H, h1L, hNa);
        ROT();
      }
      // sub1: h0_new x Wih1
      for (int i = 0; i < 14; ++i) {
        STAGE3(wpI1, i + 2, bC);
        WAITV(6);
        ACBODY(bA, i, h0H, h0L, iNa);
        ROT();
      }
      WAITV(3); ACBODY(bA, 14, h0H, h0L, iNa); ROT();
      WAITV(0); ACBODY(bA, 15, h0H, h0L, iNa);
      #undef ACBODY
    }
    __syncthreads();   // all waves done reading h1_old

    // ---- GRU-1 epilogue, in-place h1 update
    {
      float biR = bi1L[hcol], biZ = bi1L[256+hcol], biN = bi1L[512+hcol];
      float bhRb = bh1L[hcol], bhZb = bh1L[256+hcol], bhNb = bh1L[512+hcol];
      #pragma unroll
      for (int q = 0; q < 4; ++q) {
        int rbase = q*8 + l5*4;
        #pragma unroll
        for (int j = 0; j < 4; ++j) {
          int reg = q*4 + j;
          int r = rbase + j;
          float rg = fsigm(aRa[reg] + biR + bhRb);
          float zg = fsigm(aZa[reg] + biZ + bhZb);
          float ng = ftanh(iNa[reg] + biN + rg * (hNa[reg] + bhNb));
          float hold = rdpair(h1H, h1L, swz(r, hcol));
          float hnew = (1.0f - zg) * ng + zg * hold;
          wrsplit(h1H, h1L, swz(r, hcol), hnew);
        }
      }
    }
    __syncthreads();   // h1_new visible

    // ---- Phase D: qr = h1n @ Wout.T + bout, quantiles, state update
    {
      int r = tid >> 4, li = tid & 15;
      float q0 = 0.0f, q1 = 0.0f, q2 = 0.0f;
      #pragma unroll
      for (int i = 0; i < 16; ++i) {
        int h = li + i*16;
        float v = rdpair(h1H, h1L, swz(r, h));
        q0 += v * WoutL[h];
        q1 += v * WoutL[256 + h];
        q2 += v * WoutL[512 + h];
      }
      #pragma unroll
      for (int m = 1; m < 16; m <<= 1) {
        q0 += __shfl_xor(q0, m);
        q1 += __shfl_xor(q1, m);
        q2 += __shfl_xor(q2, m);
      }
      if (li == 0) {
        float qlo = q0 + boutL[0];
        float qm  = qlo + softplusf(q1 + boutL[1] - qlo);
        float qhi = qm  + softplusf(q2 + boutL[2] - qm);
        size_t b = row0 + r;
        out[b*KSTEPS + k]            = qlo;
        out[outP + b*KSTEPS + k]     = qm;
        out[2*outP + b*KSTEPS + k]   = qhi;
        float* sp = sph + r*8;
        float p1 = sp[4], p2 = sp[5];
        sp[0] = qm;
        sp[1] = (qm - p1) * 5.0f;
        sp[2] = (qm - 2.0f*p2 + p1) * 100.0f;
        sp[3] = p1; sp[4] = p2; sp[5] = qm;
      }
    }
    // no barrier needed before next step's B K-loop (reads only h0 + weights;
    // first sph/h1 consumers are >=1 barrier away)
  }
}

extern "C" void kernel_launch(void* const* d_in, const int* in_sizes, int n_in,
                              void* d_out, int out_size, void* d_ws, size_t ws_size,
                              hipStream_t stream) {
  const float* hf     = (const float*)d_in[0];
  const float* istate = (const float*)d_in[1];
  const float* W1     = (const float*)d_in[2];
  const float* b1     = (const float*)d_in[3];
  const float* W2     = (const float*)d_in[4];
  const float* b2     = (const float*)d_in[5];
  const float* Wih0   = (const float*)d_in[6];
  const float* Whh0   = (const float*)d_in[7];
  const float* bih0   = (const float*)d_in[8];
  const float* bhh0   = (const float*)d_in[9];
  const float* Wih1   = (const float*)d_in[10];
  const float* Whh1   = (const float*)d_in[11];
  const float* bih1   = (const float*)d_in[12];
  const float* bhh1   = (const float*)d_in[13];
  const float* Wout   = (const float*)d_in[14];
  const float* bout   = (const float*)d_in[15];
  float* out = (float*)d_out;
  const int B = in_sizes[0] / HDIM;   // 4096

  char* ws = (char*)d_ws;
  size_t o = 0;
  _Float16* Whh0p  = (_Float16*)(ws + o); o += 393216;
  _Float16* Wih1p  = (_Float16*)(ws + o); o += 393216;
  _Float16* Whh1p  = (_Float16*)(ws + o); o += 393216;
  _Float16* W1h    = (_Float16*)(ws + o); o += 131072;
  _Float16* W1l    = (_Float16*)(ws + o); o += 131072;
  _Float16* W2h    = (_Float16*)(ws + o); o += 262144;
  _Float16* W2l    = (_Float16*)(ws + o); o += 262144;
  _Float16* Wih0hh = (_Float16*)(ws + o); o += 393216;
  _Float16* Wih0hl = (_Float16*)(ws + o); o += 393216;
  _Float16* hfh    = (_Float16*)(ws + o); o += (size_t)B * HDIM * 2;
  _Float16* hfl    = (_Float16*)(ws + o); o += (size_t)B * HDIM * 2;
  float*    teW    = (float*)(ws + o);    o += (size_t)KSTEPS * 768 * 4;
  float*    XcT    = (float*)(ws + o);    o += (size_t)B * 768 * 4;
  if (ws_size < o) return;

  const int prep_total = 196608*3 + 65536 + 131072 + 196608 + B*HDIM + KSTEPS*768;
  prep_kernel<<<dim3((prep_total + 255) / 256), dim3(256), 0, stream>>>(
      W1, W2, Wih0, Whh0, Wih1, Whh1, hf,
      Whh0p, Wih1p, Whh1p, W1h, W1l, W2h, W2l, Wih0hh, Wih0hl, hfh, hfl, teW, B);

  xc_kernel<<<dim3(B/16, 12), dim3(64), 0, stream>>>(hfh, hfl, Wih0hh, Wih0hl, bih0, XcT, B);

  hipFuncSetAttribute((const void*)gru_main,
                      hipFuncAttributeMaxDynamicSharedMemorySize, LDS_BYTES);
  gru_main<<<dim3(B/RPB), dim3(NTHR), LDS_BYTES, stream>>>(
      istate, b1, b2, Wih0, bhh0, bih1, bhh1, Wout, bout,
      Whh0p, Wih1p, Whh1p, W1h, W1l, W2h, W2l, hfh, hfl, teW, XcT, out, B);
}

// Round 10
// 674.719 us; speedup vs baseline: 2.7476x; 1.3418x over previous
//
#include <hip/hip_runtime.h>

#define HDIM 256
#define KSTEPS 30
#define RPB 16            // rows per block (256 blocks -> all CUs busy)
#define NTHR 512          // 8 waves

typedef _Float16 f16x8 __attribute__((ext_vector_type(8)));
typedef float f32x4 __attribute__((ext_vector_type(4)));
typedef float f32x16 __attribute__((ext_vector_type(16)));

#define ZV16 (f32x16){0,0,0,0,0,0,0,0,0,0,0,0,0,0,0,0}

__device__ __forceinline__ f32x4 mfma16(f16x8 a, f16x8 b, f32x4 c) {
  return __builtin_amdgcn_mfma_f32_16x16x32_f16(a, b, c, 0, 0, 0);
}
__device__ __forceinline__ f32x16 mfma32(f16x8 a, f16x8 b, f32x16 c) {
  return __builtin_amdgcn_mfma_f32_32x32x16_f16(a, b, c, 0, 0, 0);
}

// fast transcendentals via v_exp_f32 / v_rcp_f32 (~2 ULP; threshold 0.037)
__device__ __forceinline__ float fsigm(float x) {
  return __builtin_amdgcn_rcpf(1.0f + __expf(-x));
}
__device__ __forceinline__ float ftanh(float x) {
  float t = __expf(2.0f * x);                 // inf for big x -> rcp=0 -> 1
  return 1.0f - 2.0f * __builtin_amdgcn_rcpf(t + 1.0f);
}
__device__ __forceinline__ float softplusf(float x) {
  return fmaxf(x, 0.0f) + log1pf(__expf(-fabsf(x)));
}

// swizzled byte offset for a [32][256] fp16 LDS tile (row stride 512B)
__device__ __forceinline__ int swz(int r, int c) {
  return r * 512 + ((c * 2) ^ ((r & 7) << 4));
}

__device__ __forceinline__ void wrsplit(char* hi, char* lo, int off, float v) {
  _Float16 h = (_Float16)v;
  *(_Float16*)(hi + off) = h;
  *(_Float16*)(lo + off) = (_Float16)(v - (float)h);
}
__device__ __forceinline__ float rdpair(const char* hi, const char* lo, int off) {
  return (float)*(const _Float16*)(hi + off) + (float)*(const _Float16*)(lo + off);
}

// async global->LDS, 16B per lane; dest = ldsbase + lane*16 (linear)
__device__ __forceinline__ void glds16(const _Float16* src, char* lds) {
  __builtin_amdgcn_global_load_lds(
      (const __attribute__((address_space(1))) unsigned int*)src,
      (__attribute__((address_space(3))) unsigned int*)lds, 16, 0, 0);
}

// stage one k16-tile (3 gates, 1KB each, packed contiguous) into a slab buffer
// wp is per-lane: packed wave base + lane*8
#define STAGE3(wp, idx, dst) do {                            \
  const _Float16* _s = (wp) + (idx)*1536;                    \
  glds16(_s, (dst));                                         \
  glds16(_s + 512, (dst) + 1024);                            \
  glds16(_s + 1024, (dst) + 2048);                           \
} while (0)

#define WAITV(n) do { asm volatile("s_waitcnt vmcnt(" #n ")"); \
  __builtin_amdgcn_sched_barrier(0); } while (0)

#define ROT() do { char* _t = bA; bA = bB; bB = bC; bC = _t; } while (0)

// ---------------- prep: conversions + MFMA-order weight packing + teW ----------------
// Packed recurrent-weight layout (fp16):
//   e = (((w*16 + t)*3 + g)*64 + lane)*8 + j
//   src row = w*32 + (lane&31) + g*256 ; src col = t*16 + (lane>>5)*8 + j
__global__ __launch_bounds__(256) void prep_kernel(
    const float* __restrict__ W1, const float* __restrict__ W2,
    const float* __restrict__ Wih0, const float* __restrict__ Whh0,
    const float* __restrict__ Wih1, const float* __restrict__ Whh1,
    const float* __restrict__ hf,
    _Float16* __restrict__ Whh0p, _Float16* __restrict__ Wih1p,
    _Float16* __restrict__ Whh1p,
    _Float16* __restrict__ W1h, _Float16* __restrict__ W1l,
    _Float16* __restrict__ W2h, _Float16* __restrict__ W2l,
    _Float16* __restrict__ Wih0hh, _Float16* __restrict__ Wih0hl,
    _Float16* __restrict__ hfh, _Float16* __restrict__ hfl,
    float* __restrict__ teW, int B)
{
  int e = blockIdx.x * 256 + threadIdx.x;
  if (e < 3*196608) {
    int m = e / 196608, p = e % 196608;
    int j = p & 7, lane = (p >> 3) & 63;
    int q = p >> 9;
    int g = q % 3, tt = q / 3;
    int t = tt & 15, wv = tt >> 4;
    int row = wv*32 + (lane & 31) + g*256;
    int col = t*16 + (lane >> 5)*8 + j;
    const float* src = (m == 0) ? Whh0 : (m == 1) ? Wih1 : Whh1;
    _Float16* dst = (m == 0) ? Whh0p : (m == 1) ? Wih1p : Whh1p;
    dst[p] = (_Float16)src[row*256 + col];
    return;
  } e -= 3*196608;
  if (e < 65536)  { float x = W1[e]; _Float16 h = (_Float16)x; W1h[e] = h; W1l[e] = (_Float16)(x - (float)h); return; } e -= 65536;
  if (e < 131072) { float x = W2[e]; _Float16 h = (_Float16)x; W2h[e] = h; W2l[e] = (_Float16)(x - (float)h); return; } e -= 131072;
  if (e < 196608) { int n = e >> 8, c = e & 255; float x = Wih0[n*291 + 35 + c]; _Float16 h = (_Float16)x; Wih0hh[e] = h; Wih0hl[e] = (_Float16)(x - (float)h); return; } e -= 196608;
  if (e < B*HDIM) { float x = hf[e]; _Float16 h = (_Float16)x; hfh[e] = h; hfl[e] = (_Float16)(x - (float)h); return; } e -= B*HDIM;
  if (e < KSTEPS*768) {
    int k = e / 768, n = e % 768;
    float pos = (float)k;
    const float fac = -9.210340371976184f / 31.0f;   // -ln(10000)/(TD-1)
    float acc = 0.0f;
    #pragma unroll
    for (int j = 0; j < 31; ++j) {
      int i = j >> 1;
      float ang = pos * expf((float)(2*i) * fac);
      float t = (j & 1) ? cosf(ang) : sinf(ang);
      acc += t * Wih0[n*291 + 3 + j];
    }
    acc += (pos / 30.0f) * Wih0[n*291 + 3 + 31];
    teW[e] = acc;
  }
}

// ------- XcT[n*B + r] = (hf @ Wih0[:,35:291].T)[r,n] + bih0[n]  (transposed, f32) -------
__global__ __launch_bounds__(64) void xc_kernel(
    const _Float16* __restrict__ hfh, const _Float16* __restrict__ hfl,
    const _Float16* __restrict__ Wh, const _Float16* __restrict__ Wl,
    const float* __restrict__ bih0, float* __restrict__ XcT, int B)
{
  int l = threadIdx.x, l15 = l & 15, l4 = l >> 4;
  int bm = blockIdx.x;
  int bn = blockIdx.y;
  f32x4 acc[4];
  #pragma unroll
  for (int i = 0; i < 4; ++i) acc[i] = (f32x4){0,0,0,0};
  const _Float16* ah = hfh + (size_t)(bm*16 + l15)*256 + l4*8;
  const _Float16* al = hfl + (size_t)(bm*16 + l15)*256 + l4*8;
  #pragma unroll
  for (int kk = 0; kk < 8; ++kk) {
    f16x8 aH = *(const f16x8*)(ah + kk*32);
    f16x8 aL = *(const f16x8*)(al + kk*32);
    #pragma unroll
    for (int i = 0; i < 4; ++i) {
      size_t boff = (size_t)(bn*64 + i*16 + l15)*256 + l4*8 + kk*32;
      f16x8 bH = *(const f16x8*)(Wh + boff);
      f16x8 bL = *(const f16x8*)(Wl + boff);
      acc[i] = mfma16(aH, bH, acc[i]);
      acc[i] = mfma16(aL, bH, acc[i]);
      acc[i] = mfma16(aH, bL, acc[i]);
    }
  }
  #pragma unroll
  for (int i = 0; i < 4; ++i) {
    int n = bn*64 + i*16 + l15;
    float bb = bih0[n];
    #pragma unroll
    for (int j = 0; j < 4; ++j) {
      int r = bm*16 + l4*4 + j;
      XcT[(size_t)n*B + r] = acc[i][j] + bb;
    }
  }
}

// ---------------- main persistent GRU kernel ----------------
// h tiles remain [32][256]; rows 16-31 are dead padding (MFMA C row = A row,
// so garbage rows never reach any consumed output). Zeroed once at init.
#define OFF_H0    0        // h0: hi 16KB, lo 16KB (in-place)
#define OFF_H1    32768
#define OFF_W     65536    // slab: 3 bufs x 24KB; [buf][wave 3KB][gate 1KB]
                           // (also hmid hi/lo temp during h_init)
#define OFF_WS3   139264   // 768*3 f32
#define OFF_BHH0  148480
#define OFF_BI1   151552
#define OFF_BH1   154624
#define OFF_WOUT  157696
#define OFF_SPH   160768   // 16*8 f32
#define OFF_BOUT  161792
#define LDS_BYTES 161808   // <= 163840

__global__ __launch_bounds__(NTHR) void gru_main(
    const float* __restrict__ istate,
    const float* __restrict__ b1g, const float* __restrict__ b2g,
    const float* __restrict__ Wih0, const float* __restrict__ bhh0g,
    const float* __restrict__ bih1g, const float* __restrict__ bhh1g,
    const float* __restrict__ Woutg, const float* __restrict__ boutg,
    const _Float16* __restrict__ Whh0p, const _Float16* __restrict__ Wih1p,
    const _Float16* __restrict__ Whh1p,
    const _Float16* __restrict__ W1h, const _Float16* __restrict__ W1l,
    const _Float16* __restrict__ W2h, const _Float16* __restrict__ W2l,
    const _Float16* __restrict__ hfh, const _Float16* __restrict__ hfl,
    const float* __restrict__ teW, const float* __restrict__ XcT,
    float* __restrict__ out, int B)
{
  extern __shared__ char smem[];
  char* h0H = smem + OFF_H0;  char* h0L = smem + OFF_H0 + 16384;
  char* h1H = smem + OFF_H1;  char* h1L = smem + OFF_H1 + 16384;
  float* Ws3   = (float*)(smem + OFF_WS3);
  float* bhh0L = (float*)(smem + OFF_BHH0);
  float* bi1L  = (float*)(smem + OFF_BI1);
  float* bh1L  = (float*)(smem + OFF_BH1);
  float* WoutL = (float*)(smem + OFF_WOUT);
  float* sph   = (float*)(smem + OFF_SPH);
  float* boutL = (float*)(smem + OFF_BOUT);

  const int tid = threadIdx.x;
  const int w = tid >> 6;
  const int lane = tid & 63;
  const int l15 = lane & 15;
  const int l4 = lane >> 4;
  const int l31 = lane & 31;
  const int l5 = lane >> 5;
  const int row0 = blockIdx.x * RPB;

  // wave-uniform slab bases (per-wave private 3KB region in each of 3 buffers)
  const int wsb = __builtin_amdgcn_readfirstlane(OFF_W + w * 3072);
  char* sl0 = smem + wsb;
  char* sl1 = sl0 + 24576;
  char* sl2 = sl1 + 24576;

  // per-lane packed-weight bases (tile stride 1536 elems, gate stride 512)
  const _Float16* wpB  = Whh0p + (size_t)w*24576 + lane*8;
  const _Float16* wpH1 = Whh1p + (size_t)w*24576 + lane*8;
  const _Float16* wpI1 = Wih1p + (size_t)w*24576 + lane*8;

  // ---- constants to LDS + zero dead h rows 16-31 (4 tiles x 8KB)
  for (int i = tid; i < 2304; i += NTHR) Ws3[i] = Wih0[(i/3)*291 + (i%3)];
  for (int i = tid; i < 768; i += NTHR) {
    bhh0L[i] = bhh0g[i]; bi1L[i] = bih1g[i]; bh1L[i] = bhh1g[i]; WoutL[i] = Woutg[i];
  }
  for (int i = tid; i < 2048; i += NTHR) {
    int t = i >> 9;
    int o = (i & 511) << 4;
    char* base = smem + ((t >> 1) ? OFF_H1 : OFF_H0) + ((t & 1) * 16384);
    *(f32x4*)(base + 8192 + o) = (f32x4){0,0,0,0};
  }
  if (tid < 3) boutL[tid] = boutg[tid];
  if (tid < RPB) {
    const float* is = istate + (size_t)(row0 + tid) * 3;
    float s0 = is[0], s1 = is[1], s2 = is[2];
    float* sp = sph + tid*8;
    sp[0] = s0; sp[1] = s1; sp[2] = s2;
    sp[3] = s0; sp[4] = s0; sp[5] = s0;
  }

  // ---- h_init GEMM1: relu(hf @ W1.T + b1), 16 rows -> hmid (hi/lo) in slab region
  {
    char* mH = smem + OFF_W;
    char* mL = smem + OFF_W + 16384;
    #pragma unroll
    for (int i = 0; i < 2; ++i) {
      int nt = w*2 + i;
      f32x4 acc0 = {0,0,0,0};
      const _Float16* brh = W1h + (nt*16 + l15)*256 + l4*8;
      const _Float16* brl = W1l + (nt*16 + l15)*256 + l4*8;
      const _Float16* a0h = hfh + (size_t)(row0 + l15)*256 + l4*8;
      const _Float16* a0l = hfl + (size_t)(row0 + l15)*256 + l4*8;
      #pragma unroll
      for (int kk = 0; kk < 8; ++kk) {
        f16x8 bH = *(const f16x8*)(brh + kk*32);
        f16x8 bL = *(const f16x8*)(brl + kk*32);
        f16x8 aH0 = *(const f16x8*)(a0h + kk*32);
        f16x8 aL0 = *(const f16x8*)(a0l + kk*32);
        acc0 = mfma16(aH0, bH, acc0); acc0 = mfma16(aL0, bH, acc0); acc0 = mfma16(aH0, bL, acc0);
      }
      int n = nt*16 + l15;
      float bb = b1g[n];
      #pragma unroll
      for (int j = 0; j < 4; ++j) {
        int r = l4*4 + j;
        float v = fmaxf(acc0[j] + bb, 0.0f);
        wrsplit(mH, mL, swz(r, n), v);
      }
    }
  }
  __syncthreads();

  // ---- h_init GEMM2: tanh(hmid @ W2.T + b2) -> h0 / h1 (hi/lo), 16 rows
  {
    const char* mH = smem + OFF_W;
    const char* mL = smem + OFF_W + 16384;
    #pragma unroll
    for (int i = 0; i < 4; ++i) {
      int nt = w*4 + i;
      f32x4 acc0 = {0,0,0,0};
      const _Float16* brh = W2h + (nt*16 + l15)*256 + l4*8;
      const _Float16* brl = W2l + (nt*16 + l15)*256 + l4*8;
      #pragma unroll
      for (int kk = 0; kk < 8; ++kk) {
        int kc = kk*32 + l4*8;
        f16x8 bH = *(const f16x8*)(brh + kk*32);
        f16x8 bL = *(const f16x8*)(brl + kk*32);
        f16x8 aH0 = *(const f16x8*)(mH + swz(l15, kc));
        f16x8 aL0 = *(const f16x8*)(mL + swz(l15, kc));
        acc0 = mfma16(aH0, bH, acc0); acc0 = mfma16(aL0, bH, acc0); acc0 = mfma16(aH0, bL, acc0);
      }
      int n = nt*16 + l15;
      float bb = b2g[n];
      #pragma unroll
      for (int j = 0; j < 4; ++j) {
        int r = l4*4 + j;
        float v = ftanh(acc0[j] + bb);
        if (n < 256) wrsplit(h0H, h0L, swz(r, n), v);
        else         wrsplit(h1H, h1L, swz(r, n - 256), v);
      }
    }
  }
  __syncthreads();

  const size_t outP = (size_t)B * KSTEPS;
  const int hcol = w*32 + l31;           // this thread's output column (per gate)
  const int boff = lane * 16;            // packed slab B-frag offset: conflict-free

  for (int k = 0; k < KSTEPS; ++k) {
    const float* teWk = teW + k*768;

    // ================= Phase B: gh0 = h0 @ Whh0.T (rolled, 3-buf, dist-2) ===
    f32x16 cR = ZV16, cZ = ZV16, cN = ZV16;
    {
      char *bA = sl0, *bB = sl1, *bC = sl2;
      STAGE3(wpB, 0, bA);
      STAGE3(wpB, 1, bB);
      #define BBODY(buf, kk) do {                                   \
        f16x8 bR = *(const f16x8*)((buf) + boff);                   \
        f16x8 bZ = *(const f16x8*)((buf) + 1024 + boff);            \
        f16x8 bN = *(const f16x8*)((buf) + 2048 + boff);            \
        int aoff = swz(l31, (kk)*16 + l5*8);                        \
        f16x8 aH = *(const f16x8*)(h0H + aoff);                     \
        f16x8 aL = *(const f16x8*)(h0L + aoff);                     \
        cR = mfma32(aH, bR, cR); cR = mfma32(aL, bR, cR);           \
        cZ = mfma32(aH, bZ, cZ); cZ = mfma32(aL, bZ, cZ);           \
        cN = mfma32(aH, bN, cN); cN = mfma32(aL, bN, cN);           \
      } while (0)
      for (int k16 = 0; k16 < 14; ++k16) {
        STAGE3(wpB, k16 + 2, bC);
        WAITV(6);
        BBODY(bA, k16);
        ROT();
      }
      WAITV(3); BBODY(bA, 14); ROT();
      WAITV(0); BBODY(bA, 15);
      #undef BBODY
    }
    __syncthreads();   // all waves done reading h0_old

    // ---- GRU-0 epilogue, in-place h0 update (rows 0-15 only: q<2)
    {
      float teR = teWk[hcol], teZ = teWk[256 + hcol], teN = teWk[512 + hcol];
      float wR0 = Ws3[hcol*3+0],       wR1 = Ws3[hcol*3+1],       wR2 = Ws3[hcol*3+2];
      float wZ0 = Ws3[(hcol+256)*3+0], wZ1 = Ws3[(hcol+256)*3+1], wZ2 = Ws3[(hcol+256)*3+2];
      float wN0 = Ws3[(hcol+512)*3+0], wN1 = Ws3[(hcol+512)*3+1], wN2 = Ws3[(hcol+512)*3+2];
      float bhR = bhh0L[hcol], bhZ = bhh0L[256 + hcol], bhN = bhh0L[512 + hcol];
      #pragma unroll
      for (int q = 0; q < 2; ++q) {
        int rbase = q*8 + l5*4;
        f32x4 xcR = *(const f32x4*)(XcT + (size_t)hcol*B + row0 + rbase);
        f32x4 xcZ = *(const f32x4*)(XcT + (size_t)(256 + hcol)*B + row0 + rbase);
        f32x4 xcN = *(const f32x4*)(XcT + (size_t)(512 + hcol)*B + row0 + rbase);
        #pragma unroll
        for (int j = 0; j < 4; ++j) {
          int reg = q*4 + j;
          int r = rbase + j;
          const float* sp = sph + r*8;
          float s0 = sp[0], s1 = sp[1], s2 = sp[2];
          float giR = xcR[j] + teR + s0*wR0 + s1*wR1 + s2*wR2;
          float giZ = xcZ[j] + teZ + s0*wZ0 + s1*wZ1 + s2*wZ2;
          float giN = xcN[j] + teN + s0*wN0 + s1*wN1 + s2*wN2;
          float rg = fsigm(giR + cR[reg] + bhR);
          float zg = fsigm(giZ + cZ[reg] + bhZ);
          float ng = ftanh(giN + rg * (cN[reg] + bhN));
          float hold = rdpair(h0H, h0L, swz(r, hcol));
          float hnew = (1.0f - zg) * ng + zg * hold;
          wrsplit(h0H, h0L, swz(r, hcol), hnew);
        }
      }
    }
    __syncthreads();   // h0_new visible to all

    // ===== Phase AC: K=512 concat GEMM [h1_old; h0_new] @ [Whh1; Wih1].T ====
    f32x16 aRa = ZV16, aZa = ZV16, hNa = ZV16, iNa = ZV16;
    {
      char *bA = sl0, *bB = sl1, *bC = sl2;
      STAGE3(wpH1, 0, bA);
      STAGE3(wpH1, 1, bB);
      #define ACBODY(buf, kk, AH, AL, ACN) do {                     \
        f16x8 bR = *(const f16x8*)((buf) + boff);                   \
        f16x8 bZ = *(const f16x8*)((buf) + 1024 + boff);            \
        f16x8 bN = *(const f16x8*)((buf) + 2048 + boff);            \
        int aoff = swz(l31, (kk)*16 + l5*8);                        \
        f16x8 aH = *(const f16x8*)((AH) + aoff);                    \
        f16x8 aL = *(const f16x8*)((AL) + aoff);                    \
        aRa = mfma32(aH, bR, aRa); aRa = mfma32(aL, bR, aRa);       \
        aZa = mfma32(aH, bZ, aZa); aZa = mfma32(aL, bZ, aZa);       \
        ACN = mfma32(aH, bN, ACN); ACN = mfma32(aL, bN, ACN);       \
      } while (0)
      // sub0: h1_old x Whh1 (stages cross into sub1's source near the end)
      for (int i = 0; i < 16; ++i) {
        const _Float16* sb = (i + 2 < 16) ? wpH1 : wpI1;
        STAGE3(sb, (i + 2) & 15, bC);
        WAITV(6);
        ACBODY(bA, i, h1H, h1L, hNa);
        ROT();
      }
      // sub1: h0_new x Wih1
      for (int i = 0; i < 14; ++i) {
        STAGE3(wpI1, i + 2, bC);
        WAITV(6);
        ACBODY(bA, i, h0H, h0L, iNa);
        ROT();
      }
      WAITV(3); ACBODY(bA, 14, h0H, h0L, iNa); ROT();
      WAITV(0); ACBODY(bA, 15, h0H, h0L, iNa);
      #undef ACBODY
    }
    __syncthreads();   // all waves done reading h1_old

    // ---- GRU-1 epilogue, in-place h1 update (rows 0-15 only: q<2)
    {
      float biR = bi1L[hcol], biZ = bi1L[256+hcol], biN = bi1L[512+hcol];
      float bhRb = bh1L[hcol], bhZb = bh1L[256+hcol], bhNb = bh1L[512+hcol];
      #pragma unroll
      for (int q = 0; q < 2; ++q) {
        int rbase = q*8 + l5*4;
        #pragma unroll
        for (int j = 0; j < 4; ++j) {
          int reg = q*4 + j;
          int r = rbase + j;
          float rg = fsigm(aRa[reg] + biR + bhRb);
          float zg = fsigm(aZa[reg] + biZ + bhZb);
          float ng = ftanh(iNa[reg] + biN + rg * (hNa[reg] + bhNb));
          float hold = rdpair(h1H, h1L, swz(r, hcol));
          float hnew = (1.0f - zg) * ng + zg * hold;
          wrsplit(h1H, h1L, swz(r, hcol), hnew);
        }
      }
    }
    __syncthreads();   // h1_new visible

    // ---- Phase D: qr = h1n @ Wout.T + bout (16 rows x 32 lanes)
    {
      int r = tid >> 5, li = tid & 31;
      float q0 = 0.0f, q1 = 0.0f, q2 = 0.0f;
      #pragma unroll
      for (int i = 0; i < 8; ++i) {
        int h = li + i*32;
        float v = rdpair(h1H, h1L, swz(r, h));
        q0 += v * WoutL[h];
        q1 += v * WoutL[256 + h];
        q2 += v * WoutL[512 + h];
      }
      #pragma unroll
      for (int m = 1; m < 32; m <<= 1) {
        q0 += __shfl_xor(q0, m);
        q1 += __shfl_xor(q1, m);
        q2 += __shfl_xor(q2, m);
      }
      if (li == 0) {
        float qlo = q0 + boutL[0];
        float qm  = qlo + softplusf(q1 + boutL[1] - qlo);
        float qhi = qm  + softplusf(q2 + boutL[2] - qm);
        size_t b = row0 + r;
        out[b*KSTEPS + k]            = qlo;
        out[outP + b*KSTEPS + k]     = qm;
        out[2*outP + b*KSTEPS + k]   = qhi;
        float* sp = sph + r*8;
        float p1 = sp[4], p2 = sp[5];
        sp[0] = qm;
        sp[1] = (qm - p1) * 5.0f;
        sp[2] = (qm - 2.0f*p2 + p1) * 100.0f;
        sp[3] = p1; sp[4] = p2; sp[5] = qm;
      }
    }
    // no barrier needed before next step's B K-loop (reads only h0 + weights;
    // first sph/h1 consumers are >=1 barrier away)
  }
}

extern "C" void kernel_launch(void* const* d_in, const int* in_sizes, int n_in,
                              void* d_out, int out_size, void* d_ws, size_t ws_size,
                              hipStream_t stream) {
  const float* hf     = (const float*)d_in[0];
  const float* istate = (const float*)d_in[1];
  const float* W1     = (const float*)d_in[2];
  const float* b1     = (const float*)d_in[3];
  const float* W2     = (const float*)d_in[4];
  const float* b2     = (const float*)d_in[5];
  const float* Wih0   = (const float*)d_in[6];
  const float* Whh0   = (const float*)d_in[7];
  const float* bih0   = (const float*)d_in[8];
  const float* bhh0   = (const float*)d_in[9];
  const float* Wih1   = (const float*)d_in[10];
  const float* Whh1   = (const float*)d_in[11];
  const float* bih1   = (const float*)d_in[12];
  const float* bhh1   = (const float*)d_in[13];
  const float* Wout   = (const float*)d_in[14];
  const float* bout   = (const float*)d_in[15];
  float* out = (float*)d_out;
  const int B = in_sizes[0] / HDIM;   // 4096

  char* ws = (char*)d_ws;
  size_t o = 0;
  _Float16* Whh0p  = (_Float16*)(ws + o); o += 393216;
  _Float16* Wih1p  = (_Float16*)(ws + o); o += 393216;
  _Float16* Whh1p  = (_Float16*)(ws + o); o += 393216;
  _Float16* W1h    = (_Float16*)(ws + o); o += 131072;
  _Float16* W1l    = (_Float16*)(ws + o); o += 131072;
  _Float16* W2h    = (_Float16*)(ws + o); o += 262144;
  _Float16* W2l    = (_Float16*)(ws + o); o += 262144;
  _Float16* Wih0hh = (_Float16*)(ws + o); o += 393216;
  _Float16* Wih0hl = (_Float16*)(ws + o); o += 393216;
  _Float16* hfh    = (_Float16*)(ws + o); o += (size_t)B * HDIM * 2;
  _Float16* hfl    = (_Float16*)(ws + o); o += (size_t)B * HDIM * 2;
  float*    teW    = (float*)(ws + o);    o += (size_t)KSTEPS * 768 * 4;
  float*    XcT    = (float*)(ws + o);    o += (size_t)B * 768 * 4;
  if (ws_size < o) return;

  const int prep_total = 196608*3 + 65536 + 131072 + 196608 + B*HDIM + KSTEPS*768;
  prep_kernel<<<dim3((prep_total + 255) / 256), dim3(256), 0, stream>>>(
      W1, W2, Wih0, Whh0, Wih1, Whh1, hf,
      Whh0p, Wih1p, Whh1p, W1h, W1l, W2h, W2l, Wih0hh, Wih0hl, hfh, hfl, teW, B);

  xc_kernel<<<dim3(B/16, 12), dim3(64), 0, stream>>>(hfh, hfl, Wih0hh, Wih0hl, bih0, XcT, B);

  hipFuncSetAttribute((const void*)gru_main,
                      hipFuncAttributeMaxDynamicSharedMemorySize, LDS_BYTES);
  gru_main<<<dim3(B/RPB), dim3(NTHR), LDS_BYTES, stream>>>(
      istate, b1, b2, Wih0, bhh0, bih1, bhh1, Wout, bout,
      Whh0p, Wih1p, Whh1p, W1h, W1l, W2h, W2l, hfh, hfl, teW, XcT, out, B);
}